// Round 4
// baseline (1386.411 us; speedup 1.0000x reference)
//
#include <hip/hip_runtime.h>

// Swin window attention, fused persistent-block design (R2; R4 = NaN fix).
// Shapes: B=64, RES=56, DIMS=192, HEADS=6, HD=32, WS=7, N=49, nW=64, SHIFT=3.
// Grid = 256 blocks (1/CU), each block persists over 16 windows (batch b constant
// per block). Block = 768 threads (12 waves, 3/SIMD, LDS-capped at 1 block/CU).
//
// R4 fix: Q/K rows for pad tokens (>=49) are now ZEROED at the phase-2 store
// (selection, like the V path). X LDS rows 49..63 are uninitialized garbage
// (can be NaN/Inf); R2 masked pad keys by ADDING -inf (bm), and NaN + -inf =
// NaN poisoned the softmax sum for valid queries. With K pad rows zeroed the
// score is finite, 0 + (-inf) = -inf, exp -> 0. (R1 used selection-masking so
// garbage never entered arithmetic; R2's bm-hoist changed that semantics.)
//
// R2 changes vs R1 (all epilogues vectorized via MFMA operand-role swaps; LDS
// layouts unchanged: [tok][d] row-major for X/Q/K/O, VT[d][key], P[q][key]):
//  - Q/K proj computed as D = W^T·X^T  -> C-frag has 4 contiguous d per lane ->
//    short4v LDS stores (was 48 scalar ds_write_b16 per wave).
//  - QK^T computed swapped: mfma(K,Q) = S^T -> lane holds 16 scores of ONE query;
//    softmax reduce = 2 shfl_xor (was 32 ds_bpermute); P write = 4 short4v.
//  - PV computed swapped: mfma(V^T, P^T) = O^T -> short4v O stores.
//  - out-proj swapped: mfma(Wo^T, O^T) -> float4 global stores.
//  - Persistent: next window's X global-loaded to regs during ph3, written to
//    LDS during ph4. X/O and P ping-pong between two buffers (time-disjoint),
//    so still only 3 barriers per window. bias+mask bm[2][4][4] hoisted out of
//    the window loop (loop-invariant: depends only on b).
//
// Layout facts used (verified per guide):
//   A-frag: lane holds A[m=lane&15][k=(lane>>4)*8 + j], j=0..7 (16B contig)
//   B-frag: lane holds B[k=(lane>>4)*8 + j][n=lane&15]
//   C/D   : lane holds D[m=(lane>>4)*4 + r][n=lane&15], r=0..3
// Mask quirk: reference repeats mask by batch (scores[b*64+w] gets mask[b]).

typedef __attribute__((ext_vector_type(8))) short bf16x8;
typedef __attribute__((ext_vector_type(4))) short short4v;
typedef __attribute__((ext_vector_type(4))) float f32x4;

__device__ __forceinline__ short f2bf(float x) {
  unsigned u = __builtin_bit_cast(unsigned, x);
  u += 0x7fffu + ((u >> 16) & 1u);   // RNE
  return (short)(u >> 16);
}

// ---------------- prep: weight transpose->bf16, bias expansion ----------------
__global__ void prep_kernel(const float* __restrict__ wq, const float* __restrict__ wk,
                            const float* __restrict__ wv, const float* __restrict__ wo,
                            const float* __restrict__ table,
                            short* __restrict__ wT, float* __restrict__ biasx) {
  int tid = blockIdx.x * 256 + threadIdx.x;
  if (tid < 4 * 36864) {
    int mat = tid / 36864, rem = tid % 36864;
    int k = rem / 192, n = rem % 192;
    const float* w = (mat == 0) ? wq : (mat == 1) ? wk : (mat == 2) ? wv : wo;
    wT[mat * 36864 + n * 192 + k] = f2bf(w[k * 192 + n]);
  }
  if (tid < 6 * 2401) {
    int h = tid / 2401, rem = tid % 2401;
    int q = rem / 49, k = rem % 49;
    int idx = ((q / 7) - (k / 7) + 6) * 13 + ((q % 7) - (k % 7) + 6);
    biasx[tid] = table[idx * 6 + h];
  }
}

// ---------------- main fused persistent kernel ----------------
__launch_bounds__(768, 3)
__global__ void swin_attn_kernel(const float* __restrict__ x,
                                 const short* __restrict__ wT,
                                 const float* __restrict__ biasx,
                                 const float* __restrict__ bq, const float* __restrict__ bk,
                                 const float* __restrict__ bv, const float* __restrict__ bo,
                                 float* __restrict__ out) {
  extern __shared__ short smem[];
  short* bufA = smem;            // 13824: X/O (even windows) or P strips (odd)
  short* bufB = smem + 13824;    // 13824: P strips (even windows) or X/O (odd)
  short* s_q  = smem + 27648;    // 64 x 200
  short* s_k  = smem + 40448;    // 64 x 200
  short* s_vt = smem + 53248;    // 192 x 72 (V transposed: [d][key])
  // total = 67072 shorts = 134144 B (1 block/CU)

  const int tid  = threadIdx.x;
  const int w    = tid >> 6;       // wave id 0..11
  const int lane = tid & 63;
  const int quad = lane >> 4;
  const int l15  = lane & 15;

  const int p   = blockIdx.x;       // persistent block id: windows 16p..16p+15
  const int b   = p >> 2;           // batch (constant per block)
  const int mwh = b >> 3, mww = b & 7;   // mask window coords (reference quirk!)

  const int rt = w & 3;   // token/query/key row-tile owned by this wave
  const int g  = w >> 2;  // dout-third (ph2/ph4) == head-pair (ph3)

  const f32x4 zero4 = {0.f, 0.f, 0.f, 0.f};
  const float NEGINF = -__builtin_inff();
  const float SCALE = 0.17677669529663687f;  // 1/sqrt(32)

  // ---- hoisted phase-1 per-item constants (window-independent) ----
  int th_[4], tw_[4], wa_[4], c4_[4];
#pragma unroll
  for (int it = 0; it < 4; ++it) {
    int i = tid + it * 768;
    int t = i / 48, c4 = i - t * 48;
    th_[it] = t / 7; tw_[it] = t - th_[it] * 7;
    c4_[it] = c4; wa_[it] = t * 200 + c4 * 4;
  }
  const bool has4 = (tid < 48);   // 49*48 = 2352 = 768*3 + 48

  // token owned in ph2 Q/K store and ph4 (swapped layouts): rt*16 + l15
  const int token = rt * 16 + l15;
  const bool tokv = (token < 49);

  // ---- hoisted phase-3 bias+mask (loop-invariant: depends only on b) ----
  // bm[hh][mt][r] for query = rt*16+l15, key = mt*16+quad*4+r, head = 2g+hh.
  const int qc  = tokv ? token : 48;
  const int qth = qc / 7, qtw = qc - qth * 7;
  const int cq  = ((mwh == 7) ? (1 + (qth >= 4)) : 0) * 3
                + ((mww == 7) ? (1 + (qtw >= 4)) : 0);
  float bm[2][4][4];
#pragma unroll
  for (int hh = 0; hh < 2; ++hh) {
    const int h = g * 2 + hh;
#pragma unroll
    for (int mt = 0; mt < 4; ++mt)
#pragma unroll
      for (int r = 0; r < 4; ++r) {
        int key = mt * 16 + quad * 4 + r;
        if (key > 48) {
          bm[hh][mt][r] = NEGINF;
        } else {
          int kth = key / 7, ktw = key - kth * 7;
          int ck = ((mwh == 7) ? (1 + (kth >= 4)) : 0) * 3
                 + ((mww == 7) ? (1 + (ktw >= 4)) : 0);
          bm[hh][mt][r] = biasx[h * 2401 + qc * 49 + key] + ((ck == cq) ? 0.f : -1000.f);
        }
      }
  }

  // ---- hoisted phase-4 token coords ----
  const int tt  = tokv ? token : 0;
  const int tth = tt / 7, ttw = tt - tth * 7;

  // ---- prologue: load window 0's X -> bufA ----
  {
    const int wi0 = (p & 3) * 16;
    const int hb = (wi0 >> 3) * 7 + 3, wb = (wi0 & 7) * 7 + 3;
#pragma unroll
    for (int it = 0; it < 3; ++it) {
      int gh = hb + th_[it]; if (gh >= 56) gh -= 56;
      int gw = wb + tw_[it]; if (gw >= 56) gw -= 56;
      float4 v = *(const float4*)(x + (((b * 56 + gh) * 56 + gw) * 192 + c4_[it] * 4));
      short4v s;
      s[0] = f2bf(v.x); s[1] = f2bf(v.y); s[2] = f2bf(v.z); s[3] = f2bf(v.w);
      *(short4v*)(bufA + wa_[it]) = s;
    }
    if (has4) {
      int gh = hb + th_[3]; if (gh >= 56) gh -= 56;
      int gw = wb + tw_[3]; if (gw >= 56) gw -= 56;
      float4 v = *(const float4*)(x + (((b * 56 + gh) * 56 + gw) * 192 + c4_[3] * 4));
      short4v s;
      s[0] = f2bf(v.x); s[1] = f2bf(v.y); s[2] = f2bf(v.z); s[3] = f2bf(v.w);
      *(short4v*)(bufA + wa_[3]) = s;
    }
  }
  __syncthreads();

  float4 px0, px1, px2, px3;

#pragma unroll 1
  for (int win = 0; win < 16; ++win) {
    short* xw   = (win & 1) ? bufB : bufA;   // X (ph2), then O (ph3/ph4)
    short* pbuf = (win & 1) ? bufA : bufB;   // P strips (ph3), then next X (ph4)
    const int wi  = (p & 3) * 16 + win;
    const int wwh = wi >> 3, www = wi & 7;

    // ---- phase 2: QKV projections ----
    // Shared X fragments for this wave's token-tile (A-frag for V, B-frag for Q/K).
    bf16x8 xf[6];
#pragma unroll
    for (int ks = 0; ks < 6; ++ks)
      xf[ks] = *(const bf16x8*)(xw + (rt * 16 + l15) * 200 + ks * 32 + quad * 8);

    // Q, K swapped: D[m=dout][n=token] = W^T · X^T -> short4v stores.
    // Pad tokens (>=49) store 0: X rows 49..63 are uninitialized garbage (may be
    // NaN/Inf); finite zeros keep the -inf bm addition in ph3 NaN-free.
#pragma unroll
    for (int mat = 0; mat < 2; ++mat) {
      const short* wt = wT + mat * 36864;
      const float* bp = mat ? bk : bq;
      short* dst = mat ? s_k : s_q;
#pragma unroll
      for (int j = 0; j < 4; ++j) {
        const int dbase = (g * 4 + j) * 16;
        const short* wrow = wt + (dbase + l15) * 192;
        f32x4 acc = zero4;
#pragma unroll
        for (int ks = 0; ks < 6; ++ks) {
          bf16x8 wfr = *(const bf16x8*)(wrow + ks * 32 + quad * 8);
          acc = __builtin_amdgcn_mfma_f32_16x16x32_bf16(wfr, xf[ks], acc, 0, 0, 0);
        }
        const float4 b4 = *(const float4*)(bp + dbase + quad * 4);
        short4v st;
        st[0] = f2bf(tokv ? acc[0] + b4.x : 0.f);
        st[1] = f2bf(tokv ? acc[1] + b4.y : 0.f);
        st[2] = f2bf(tokv ? acc[2] + b4.z : 0.f);
        st[3] = f2bf(tokv ? acc[3] + b4.w : 0.f);
        *(short4v*)(dst + (rt * 16 + l15) * 200 + dbase + quad * 4) = st;
      }
    }
    // V unswapped: D[m=key][n=dout] -> short4v stores into VT[d][key].
    {
      const short* wt = wT + 2 * 36864;
#pragma unroll
      for (int j = 0; j < 4; ++j) {
        const int dbase = (g * 4 + j) * 16;
        const short* wrow = wt + (dbase + l15) * 192;
        f32x4 acc = zero4;
#pragma unroll
        for (int ks = 0; ks < 6; ++ks) {
          bf16x8 wfr = *(const bf16x8*)(wrow + ks * 32 + quad * 8);
          acc = __builtin_amdgcn_mfma_f32_16x16x32_bf16(xf[ks], wfr, acc, 0, 0, 0);
        }
        const float bvv = bv[dbase + l15];
        short4v st;
#pragma unroll
        for (int r = 0; r < 4; ++r) {
          int key = rt * 16 + quad * 4 + r;
          // zero pad keys >= 49 (P pad cols are 0; 0*NaN would poison otherwise)
          st[r] = f2bf((key < 49) ? (acc[r] + bvv) : 0.f);
        }
        *(short4v*)(s_vt + (dbase + l15) * 72 + rt * 16 + quad * 4) = st;
      }
    }
    __syncthreads();   // B1: QKV ready; X dead

    // ---- issue next window's X loads (latency hides under phase 3) ----
    if (win < 15) {
      const int wi2 = wi + 1;
      const int hb = (wi2 >> 3) * 7 + 3, wb = (wi2 & 7) * 7 + 3;
      {
        int gh = hb + th_[0]; if (gh >= 56) gh -= 56;
        int gw = wb + tw_[0]; if (gw >= 56) gw -= 56;
        px0 = *(const float4*)(x + (((b * 56 + gh) * 56 + gw) * 192 + c4_[0] * 4));
      }
      {
        int gh = hb + th_[1]; if (gh >= 56) gh -= 56;
        int gw = wb + tw_[1]; if (gw >= 56) gw -= 56;
        px1 = *(const float4*)(x + (((b * 56 + gh) * 56 + gw) * 192 + c4_[1] * 4));
      }
      {
        int gh = hb + th_[2]; if (gh >= 56) gh -= 56;
        int gw = wb + tw_[2]; if (gw >= 56) gw -= 56;
        px2 = *(const float4*)(x + (((b * 56 + gh) * 56 + gw) * 192 + c4_[2] * 4));
      }
      if (has4) {
        int gh = hb + th_[3]; if (gh >= 56) gh -= 56;
        int gw = wb + tw_[3]; if (gw >= 56) gw -= 56;
        px3 = *(const float4*)(x + (((b * 56 + gh) * 56 + gw) * 192 + c4_[3] * 4));
      }
    }

    // ---- phase 3: attention (wave = query-tile rt x head-pair g) ----
    short* myp = pbuf + w * 1152;   // wave-private 16x72 P strip
#pragma unroll
    for (int hh = 0; hh < 2; ++hh) {
      const int d0 = (g * 2 + hh) * 32;
      // swapped QK^T: S^T[key][query] = mfma(A=K rows, B=Q^T)
      bf16x8 qf = *(const bf16x8*)(s_q + (rt * 16 + l15) * 200 + d0 + quad * 8);
      float sv[4][4];
#pragma unroll
      for (int mt = 0; mt < 4; ++mt) {
        bf16x8 kf = *(const bf16x8*)(s_k + (mt * 16 + l15) * 200 + d0 + quad * 8);
        f32x4 s = __builtin_amdgcn_mfma_f32_16x16x32_bf16(kf, qf, zero4, 0, 0, 0);
#pragma unroll
        for (int r = 0; r < 4; ++r)
          sv[mt][r] = s[r] * SCALE + bm[hh][mt][r];
      }
      // softmax for query l15: 16 lane-local values, reduce across quads (2 shfl)
      float mx = sv[0][0];
#pragma unroll
      for (int mt = 0; mt < 4; ++mt)
#pragma unroll
        for (int r = 0; r < 4; ++r) mx = fmaxf(mx, sv[mt][r]);
      mx = fmaxf(mx, __shfl_xor(mx, 16));
      mx = fmaxf(mx, __shfl_xor(mx, 32));
      float s0 = 0.f;
#pragma unroll
      for (int mt = 0; mt < 4; ++mt)
#pragma unroll
        for (int r = 0; r < 4; ++r) {
          float e = __expf(sv[mt][r] - mx);
          sv[mt][r] = e;
          s0 += e;
        }
      s0 += __shfl_xor(s0, 16);
      s0 += __shfl_xor(s0, 32);
      const float inv = 1.0f / s0;   // normalization folded into O epilogue
      // P -> LDS (unnormalized, bf16). Same-wave RAW: DS in wave order, no barrier.
#pragma unroll
      for (int mt = 0; mt < 4; ++mt) {
        short4v st;
#pragma unroll
        for (int r = 0; r < 4; ++r) st[r] = f2bf(sv[mt][r]);
        *(short4v*)(myp + l15 * 72 + mt * 16 + quad * 4) = st;
      }
      // swapped PV: O^T[d][query] = mfma(A=V^T rows, B=P^T)
#pragma unroll
      for (int mt2 = 0; mt2 < 2; ++mt2) {
        f32x4 o = zero4;
#pragma unroll
        for (int ks = 0; ks < 2; ++ks) {
          bf16x8 vfr = *(const bf16x8*)(s_vt + (d0 + mt2 * 16 + l15) * 72 + ks * 32 + quad * 8);
          bf16x8 pfr = *(const bf16x8*)(myp + l15 * 72 + ks * 32 + quad * 8);
          o = __builtin_amdgcn_mfma_f32_16x16x32_bf16(vfr, pfr, o, 0, 0, 0);
        }
        short4v st;
#pragma unroll
        for (int r = 0; r < 4; ++r) st[r] = f2bf(o[r] * inv);
        *(short4v*)(xw + (rt * 16 + l15) * 200 + d0 + mt2 * 16 + quad * 4) = st;
      }
    }
    __syncthreads();   // B2: O ready (cross-wave); P strips dead

    // ---- phase 4: out projection (swapped) + next-X LDS write ----
    bf16x8 ao[6];
#pragma unroll
    for (int ks = 0; ks < 6; ++ks)
      ao[ks] = *(const bf16x8*)(xw + (rt * 16 + l15) * 200 + ks * 32 + quad * 8);

    // write next window's X into pbuf (P strips dead after B2; overlaps ph4 MFMAs)
    if (win < 15) {
      short4v s;
      s[0] = f2bf(px0.x); s[1] = f2bf(px0.y); s[2] = f2bf(px0.z); s[3] = f2bf(px0.w);
      *(short4v*)(pbuf + wa_[0]) = s;
      s[0] = f2bf(px1.x); s[1] = f2bf(px1.y); s[2] = f2bf(px1.z); s[3] = f2bf(px1.w);
      *(short4v*)(pbuf + wa_[1]) = s;
      s[0] = f2bf(px2.x); s[1] = f2bf(px2.y); s[2] = f2bf(px2.z); s[3] = f2bf(px2.w);
      *(short4v*)(pbuf + wa_[2]) = s;
      if (has4) {
        s[0] = f2bf(px3.x); s[1] = f2bf(px3.y); s[2] = f2bf(px3.z); s[3] = f2bf(px3.w);
        *(short4v*)(pbuf + wa_[3]) = s;
      }
    }

    // out^T[col][token] = mfma(A=Wo^T rows, B=O^T) -> float4 global stores
    int rowbase = 0;
    if (tokv) {
      int gh = wwh * 7 + tth + 3; if (gh >= 56) gh -= 56;
      int gw = www * 7 + ttw + 3; if (gw >= 56) gw -= 56;
      rowbase = ((b * 56 + gh) * 56 + gw) * 192;
    }
    const short* wto = wT + 3 * 36864;
#pragma unroll
    for (int j = 0; j < 4; ++j) {
      const int cbase = (g * 4 + j) * 16;
      const short* wrow = wto + (cbase + l15) * 192;
      f32x4 acc = zero4;
#pragma unroll
      for (int ks = 0; ks < 6; ++ks) {
        bf16x8 wfr = *(const bf16x8*)(wrow + ks * 32 + quad * 8);
        acc = __builtin_amdgcn_mfma_f32_16x16x32_bf16(wfr, ao[ks], acc, 0, 0, 0);
      }
      const float4 b4 = *(const float4*)(bo + cbase + quad * 4);
      if (tokv) {
        float4 v;
        v.x = acc[0] + b4.x; v.y = acc[1] + b4.y;
        v.z = acc[2] + b4.z; v.w = acc[3] + b4.w;
        *(float4*)(out + rowbase + cbase + quad * 4) = v;
      }
    }
    __syncthreads();   // B3: next-X ready; this window's LDS reads all done
  }
}

extern "C" void kernel_launch(void* const* d_in, const int* in_sizes, int n_in,
                              void* d_out, int out_size, void* d_ws, size_t ws_size,
                              hipStream_t stream) {
  const float* x     = (const float*)d_in[0];
  const float* table = (const float*)d_in[1];
  const float* wq    = (const float*)d_in[2];
  const float* bq    = (const float*)d_in[3];
  const float* wk    = (const float*)d_in[4];
  const float* bk    = (const float*)d_in[5];
  const float* wv    = (const float*)d_in[6];
  const float* bv    = (const float*)d_in[7];
  const float* wo    = (const float*)d_in[8];
  const float* bo    = (const float*)d_in[9];
  float* out = (float*)d_out;

  short* wT    = (short*)d_ws;                       // 294912 B
  float* biasx = (float*)((char*)d_ws + 294912);     // 57624 B

  prep_kernel<<<576, 256, 0, stream>>>(wq, wk, wv, wo, table, wT, biasx);

  const int smem_bytes = 67072 * 2;  // 134144
  (void)hipFuncSetAttribute(reinterpret_cast<const void*>(swin_attn_kernel),
                            hipFuncAttributeMaxDynamicSharedMemorySize, smem_bytes);
  swin_attn_kernel<<<256, 768, smem_bytes, stream>>>(x, wT, biasx, bq, bk, bv, bo, out);
}